// Round 3
// baseline (374.827 us; speedup 1.0000x reference)
//
#include <hip/hip_runtime.h>

// ChannelBlockImportanceGate: B=8, C=256, H=W=132, BLOCK=8, KEEP_RATIO=0.25
// Output = hard top-72 block mask (of 289 blocks) upsampled 8x, per (b,c) plane.
// Straight-through soft blend cancels numerically -> output is the hard mask.
//
// R2: (a) linear float4 streaming for loads AND stores (R1's strided patch
// loads raised FETCH 70->91MB); (b) fp64 per-float4 partials in LDS, block
// reduce + rank done by WAVE 0 ONLY -> j-loop broadcast ds_reads happen once
// per block (289) instead of once per active wave (1445) -- the hidden
// serial LDS-pipe cost in R0/R1; (c) 3 barriers total (R0 had 34).

#define HH 132
#define WW 132
#define NB 17           // blocks per side
#define TOTAL 289       // NB*NB
#define KEEP 72         // round(289*0.25)
#define NT 256
#define ROW4 (WW / 4)   // 33 float4 per row
#define NV4 (HH * ROW4) // 4356 float4 per plane

__global__ __launch_bounds__(NT, 8)
void gate_kernel(const float* __restrict__ feats,
                 const int* __restrict__ enabled_p,
                 float* __restrict__ out) {
    const int plane = blockIdx.x;
    const int t = threadIdx.x;
    const float4* __restrict__ fp4 = (const float4*)(feats + (size_t)plane * (HH * WW));
    float4* __restrict__ op4 = (float4*)(out + (size_t)plane * (HH * WW));

    __shared__ double s_part[NV4];    // 34848 B: fp64 |sum| per float4
    __shared__ double s_score[TOTAL]; // 2312 B: exact block sums
    __shared__ float  s_hard[TOTAL];  // 1156 B: 0/1 mask

    // ---- P1: linear stream, one fp64 partial per float4 ----
    for (int k = 0; k < 18; ++k) {
        const int v = t + (k << 8);
        if (v < NV4) {
            const float4 a = fp4[v];
            s_part[v] = (double)fabsf(a.x) + (double)fabsf(a.y)
                      + (double)fabsf(a.z) + (double)fabsf(a.w);
        }
    }
    __syncthreads();

    // ---- P1b: wave 0 reduces partials -> block scores (exact fp64) ----
    double si[5];
    int idx[5], rank[5];
    if (t < 64) {
        #pragma unroll
        for (int q = 0; q < 5; ++q) {
            const int i = t + (q << 6);
            idx[q] = i; si[q] = -1.0; rank[q] = TOTAL;
            if (i < TOTAL) {
                const int br = i / NB;            // magic-mul div
                const int bc = i - br * NB;
                const int nr = (br == NB - 1) ? 4 : 8;   // rows 128..131 only
                const int two = (bc == NB - 1) ? 0 : 1;  // last block-col: 1 partial
                int base = (br * 8) * ROW4 + bc * 2;
                double s = 0.0;
                for (int r = 0; r < nr; ++r) {
                    s += s_part[base];
                    if (two) s += s_part[base + 1];
                    base += ROW4;
                }
                si[q] = s;
                s_score[i] = s;
            }
        }
    }
    __syncthreads();   // all threads: publish s_score (and keep waves convergent)

    // ---- P2: wave 0 ranks all 289 (one broadcast j-loop for 5 i's/lane) ----
    if (t < 64) {
        #pragma unroll
        for (int q = 0; q < 5; ++q) rank[q] = 0;
        for (int j = 0; j < TOTAL; ++j) {
            const double sj = s_score[j];      // broadcast LDS read
            #pragma unroll
            for (int q = 0; q < 5; ++q) {
                rank[q] += (int)((sj > si[q]) ||
                                 ((sj == si[q]) && (j < idx[q])));
            }
        }
        const int en = *enabled_p;
        #pragma unroll
        for (int q = 0; q < 5; ++q) {
            if (idx[q] < TOTAL)
                s_hard[idx[q]] = (!en || rank[q] < KEEP) ? 1.0f : 0.0f;
        }
    }
    __syncthreads();

    // ---- P3: upsample 8x, linear float4 stores ----
    for (int k = 0; k < 18; ++k) {
        const int v = t + (k << 8);
        if (v < NV4) {
            const int row = v / ROW4;          // magic-mul div by 33
            const int c4 = v - row * ROW4;
            const float m = s_hard[(row >> 3) * NB + (c4 >> 1)];
            op4[v] = make_float4(m, m, m, m);
        }
    }
}

extern "C" void kernel_launch(void* const* d_in, const int* in_sizes, int n_in,
                              void* d_out, int out_size, void* d_ws, size_t ws_size,
                              hipStream_t stream) {
    const float* feats = (const float*)d_in[0];
    const int* enabled = (const int*)d_in[1];
    float* out = (float*)d_out;
    gate_kernel<<<8 * 256, NT, 0, stream>>>(feats, enabled, out);
}

// Round 5
// 287.559 us; speedup vs baseline: 1.3035x; 1.3035x over previous
//
#include <hip/hip_runtime.h>

// ChannelBlockImportanceGate: B=8, C=256, H=W=132, BLOCK=8, KEEP_RATIO=0.25
// Output = hard top-72 block mask (of 289 blocks) upsampled 8x per plane.
// Straight-through soft blend cancels numerically -> output is the hard mask.
//
// R4: fix R3's coverage bug (iteration stride was i*256; with 2 lanes/block
// 256 threads score 128 blocks/iter -> stride i*128, 3 iters for 289).
// Structure: register-only scoring, 2 lanes per 8x8 block (left/right float4
// column x 8 rows), shfl_xor pair reduce, only 289 fp64 scores + 289 fp32
// mask in LDS (3.5 KB -> 8 wg/CU). Wave 0 ranks via broadcast LDS reads.

#define HH 132
#define WW 132
#define NB 17           // blocks per side
#define TOTAL 289       // NB*NB
#define KEEP 72         // round(289*0.25)
#define NT 256
#define ROW4 33         // float4 per row
#define NV4 4356        // float4 per plane (132*33)

__global__ __launch_bounds__(NT, 8)
void gate_kernel(const float* __restrict__ feats,
                 const int* __restrict__ enabled_p,
                 float* __restrict__ out) {
    const int plane = blockIdx.x;
    const int t = threadIdx.x;
    const int lane = t & 63;
    const int wave = t >> 6;
    const float4* __restrict__ fp4 = (const float4*)(feats + (size_t)plane * (HH * WW));
    float4* __restrict__ op4 = (float4*)(out + (size_t)plane * (HH * WW));

    const int en = *enabled_p;        // uniform s_load, issued early

    __shared__ double s_score[TOTAL]; // 2312 B
    __shared__ float  s_hard[TOTAL];  // 1156 B

    // ---- P1: 2 lanes per block; 128 blocks scored per iteration ----
    #pragma unroll
    for (int i = 0; i < 3; ++i) {
        const int g = (i << 7) + (wave << 5) + (lane >> 1);  // block id
        if (g < TOTAL) {
            const int br = g / NB;            // magic-mul div
            const int bc = g - br * NB;
            const int c4 = 2 * bc + (lane & 1);
            const int nr = (br == NB - 1) ? 4 : 8;
            double acc = 0.0;
            if (c4 < ROW4) {                  // bc==16 odd lane: no column
                const float4* p = fp4 + (size_t)(br * 8) * ROW4 + c4;
                #pragma unroll
                for (int r = 0; r < 8; ++r) {
                    if (r < nr) {
                        const float4 a = p[0];
                        acc += (double)fabsf(a.x) + (double)fabsf(a.y)
                             + (double)fabsf(a.z) + (double)fabsf(a.w);
                    }
                    p += ROW4;
                }
            }
            acc += __shfl_xor(acc, 1);        // pair reduce (guard uniform/pair)
            if ((lane & 1) == 0) s_score[g] = acc;  // exact fp64 block sum
        }
    }
    __syncthreads();

    // ---- P2: wave 0 ranks all 289 (broadcast LDS reads = conflict-free) ----
    if (wave == 0) {
        double si[5]; int rk[5];
        #pragma unroll
        for (int q = 0; q < 5; ++q) {
            const int i = lane + (q << 6);
            si[q] = (i < TOTAL) ? s_score[i] : -1.0;
            rk[q] = 0;
        }
        for (int j = 0; j < TOTAL; ++j) {
            const double sj = s_score[j];
            #pragma unroll
            for (int q = 0; q < 5; ++q) {
                const int i = lane + (q << 6);
                rk[q] += (int)((sj > si[q]) || ((sj == si[q]) && (j < i)));
            }
        }
        #pragma unroll
        for (int q = 0; q < 5; ++q) {
            const int i = lane + (q << 6);
            if (i < TOTAL) s_hard[i] = (!en || rk[q] < KEEP) ? 1.0f : 0.0f;
        }
    }
    __syncthreads();

    // ---- P3: upsample 8x, linear float4 stores (4-aligned quads never
    // cross an 8-wide block boundary). ----
    #pragma unroll
    for (int k = 0; k < 18; ++k) {
        const int v = t + (k << 8);
        if (v < NV4) {
            const int row = v / ROW4;          // magic-mul div by 33
            const int c4 = v - row * ROW4;
            const float m = s_hard[(row >> 3) * NB + (c4 >> 1)];
            op4[v] = make_float4(m, m, m, m);
        }
    }
}

extern "C" void kernel_launch(void* const* d_in, const int* in_sizes, int n_in,
                              void* d_out, int out_size, void* d_ws, size_t ws_size,
                              hipStream_t stream) {
    const float* feats = (const float*)d_in[0];
    const int* enabled = (const int*)d_in[1];
    float* out = (float*)d_out;
    gate_kernel<<<8 * 256, NT, 0, stream>>>(feats, enabled, out);
}